// Round 14
// baseline (193.839 us; speedup 1.0000x reference)
//
#include <hip/hip_runtime.h>
#include <hip/hip_fp16.h>

// GraphSAGE 3-layer encoder, MI355X.
// Transform-then-aggregate (mean agg is linear), CSR via atomic-free radix
// partition (R4). fp16 Y gather operand (R5), group-per-node aggregate (R6),
// unroll x4 (R7), fp16 activation chain (R8), swapped-operand MFMA GEMM with
// LDS-staged weights (R9), slice-ordered adjacency (R10).
// R11-R13: fuse aggregate_l + gemm_{l+1} (row-aligned producer/consumer) via
// an LDS H-tile: HA/HB buffers deleted (~50MB glue traffic), 11 -> 9 launches.
// Y double-buffered (cross-block gathers); Z strictly row-in-place.

#define MAXB 512    // max node buckets (bucket = 256 nodes); N <= 131072
#define NBLK 512    // partition blocks (2 per CU)
#define NSLICE 8    // src slices (16384 nodes = 2MB fp16-d64 each)

typedef _Float16 f16;
typedef __attribute__((ext_vector_type(4))) _Float16 f16x4;
typedef __attribute__((ext_vector_type(8))) _Float16 f16x8;
typedef __attribute__((ext_vector_type(4))) float f32x4;

// ---- pass 1: per-block histogram over dst buckets ----
__global__ __launch_bounds__(256) void hist_k(const int* __restrict__ dst, int E,
                                              int nb, int* __restrict__ ghist) {
    __shared__ int h[MAXB];
    for (int i = threadIdx.x; i < nb; i += 256) h[i] = 0;
    __syncthreads();
    int chunk = (E + NBLK - 1) / NBLK;
    int e0 = blockIdx.x * chunk, e1 = min(e0 + chunk, E);
    for (int e = e0 + threadIdx.x; e < e1; e += 256) atomicAdd(&h[dst[e] >> 8], 1);
    __syncthreads();
    for (int i = threadIdx.x; i < nb; i += 256) ghist[blockIdx.x * MAXB + i] = h[i];
}

// ---- pass 2a: per-bucket exclusive scan over NBLK block counts (in place) ----
__global__ __launch_bounds__(512) void col_scan_k(int* __restrict__ ghist,
                                                  int* __restrict__ colsum) {
    int bucket = blockIdx.x;
    int t = threadIdx.x;
    __shared__ int s[NBLK];
    int v = ghist[t * MAXB + bucket];
    s[t] = v;
    __syncthreads();
    for (int off = 1; off < NBLK; off <<= 1) {
        int x = (t >= off) ? s[t - off] : 0;
        __syncthreads();
        s[t] += x;
        __syncthreads();
    }
    ghist[t * MAXB + bucket] = s[t] - v;  // exclusive prefix for this block
    if (t == NBLK - 1) colsum[bucket] = s[NBLK - 1];
}

// ---- pass 2b: exclusive scan of bucket totals ----
__global__ __launch_bounds__(512) void bucket_scan_k(const int* __restrict__ colsum,
                                                     int* __restrict__ bbase, int nb) {
    __shared__ int s[512];
    int t = threadIdx.x;
    int v = (t < nb) ? colsum[t] : 0;
    s[t] = v;
    __syncthreads();
    for (int off = 1; off < 512; off <<= 1) {
        int x = (t >= off) ? s[t - off] : 0;
        __syncthreads();
        s[t] += x;
        __syncthreads();
    }
    if (t < nb) bbase[t] = s[t] - v;
}

// ---- pass 3: scatter edges into private contiguous sub-ranges ----
__global__ __launch_bounds__(256) void partition_k(const int* __restrict__ src,
                                                   const int* __restrict__ dst,
                                                   const int* __restrict__ ghist,
                                                   const int* __restrict__ bbase,
                                                   unsigned* __restrict__ pairs,
                                                   int E, int nb) {
    __shared__ int cur[MAXB];
    for (int i = threadIdx.x; i < nb; i += 256)
        cur[i] = bbase[i] + ghist[blockIdx.x * MAXB + i];
    __syncthreads();
    int chunk = (E + NBLK - 1) / NBLK;
    int e0 = blockIdx.x * chunk, e1 = min(e0 + chunk, E);
    for (int e = e0 + threadIdx.x; e < e1; e += 256) {
        int d = dst[e];
        int b = d >> 8;
        int pos = atomicAdd(&cur[b], 1);               // LDS atomic only
        pairs[pos] = ((unsigned)(d & 255) << 24) | (unsigned)src[e];
    }
}

// ---- pass 4: per-(node,slice) count + scan -> rowptr + slice-ordered adj ----
__global__ __launch_bounds__(256) void bucket_fill2_k(const unsigned* __restrict__ pairs,
                                                      const int* __restrict__ bbase,
                                                      const int* __restrict__ colsum,
                                                      int* __restrict__ rowptr,
                                                      int* __restrict__ adj,
                                                      int N, int E) {
    int b = blockIdx.x, t = threadIdx.x;
    int node0 = b << 8;
    int nloc = min(256, N - node0);
    int e0 = bbase[b];
    int e1 = e0 + colsum[b];
    __shared__ int cnt[256 * NSLICE];   // 8 KB
    __shared__ int base[256 * NSLICE];  // 8 KB
    __shared__ int bs[256];
#pragma unroll
    for (int k = 0; k < NSLICE; k++) cnt[t * NSLICE + k] = 0;
    __syncthreads();
    for (int e = e0 + t; e < e1; e += 256) {
        unsigned p = pairs[e];
        int local = p >> 24;
        int s = (int)((p & 0xFFFFFFu) >> 14);
        atomicAdd(&cnt[local * NSLICE + s], 1);
    }
    __syncthreads();
    int lv[NSLICE];
    int lsum = 0;
#pragma unroll
    for (int k = 0; k < NSLICE; k++) { lv[k] = cnt[t * NSLICE + k]; lsum += lv[k]; }
    bs[t] = lsum;
    __syncthreads();
    for (int off = 1; off < 256; off <<= 1) {
        int x = (t >= off) ? bs[t - off] : 0;
        __syncthreads();
        bs[t] += x;
        __syncthreads();
    }
    int run = e0 + bs[t] - lsum;  // exclusive prefix at this node's first key
    if (t < nloc) rowptr[node0 + t] = run;
    if (b == 0 && t == 0) rowptr[N] = E;
#pragma unroll
    for (int k = 0; k < NSLICE; k++) { base[t * NSLICE + k] = run; run += lv[k]; }
#pragma unroll
    for (int k = 0; k < NSLICE; k++) cnt[t * NSLICE + k] = 0;
    __syncthreads();
    for (int e = e0 + t; e < e1; e += 256) {
        unsigned p = pairs[e];
        int local = p >> 24;
        int srcv = (int)(p & 0xFFFFFFu);
        int key = local * NSLICE + (srcv >> 14);
        int pos = base[key] + atomicAdd(&cnt[key], 1);  // LDS atomic only
        adj[pos] = srcv;
    }
}

// ---------------- shared helpers ----------------

__device__ inline f16x8 cvt2h(float4 a, float4 b) {
    f16x8 o;
    o[0] = (_Float16)a.x; o[1] = (_Float16)a.y; o[2] = (_Float16)a.z; o[3] = (_Float16)a.w;
    o[4] = (_Float16)b.x; o[5] = (_Float16)b.y; o[6] = (_Float16)b.z; o[7] = (_Float16)b.w;
    return o;
}

// ---------------- standalone MFMA dual GEMM (layer 0) ----------------
// K = 64. Block = 256 rows (4 waves x 4 row-tiles of 16). Weights staged fp16
// in LDS. SWAPPED mfma(W,H): D lane l reg r -> row (l&15), col kg*4+r.

template <int DOUT, bool AFP32, bool ZF16>
__global__ __launch_bounds__(256) void gemm_mfma_k(const void* __restrict__ A,
                                                   const float* __restrict__ Wl,
                                                   const float* __restrict__ Wr,
                                                   const float* __restrict__ bias,
                                                   __half* __restrict__ Yp,
                                                   void* __restrict__ Zp, int N) {
    constexpr int DOUT2 = 2 * DOUT;
    constexpr int NCT = DOUT2 / 16;
    constexpr int WST = 72;
    __shared__ f16 wlds[DOUT2 * WST];
    int t = threadIdx.x;

    for (int i = t; i < DOUT2 * 16; i += 256) {
        int col = i >> 4, j4 = i & 15;
        const float* wsrc = (col < DOUT) ? (Wl + (size_t)col * 64)
                                         : (Wr + (size_t)(col - DOUT) * 64);
        float4 w = *reinterpret_cast<const float4*>(wsrc + j4 * 4);
        f16x4 o;
        o[0] = (_Float16)w.x; o[1] = (_Float16)w.y;
        o[2] = (_Float16)w.z; o[3] = (_Float16)w.w;
        *reinterpret_cast<f16x4*>(&wlds[col * WST + j4 * 4]) = o;
    }
    __syncthreads();

    int lane = t & 63, wv = t >> 6;
    int r16 = lane & 15;
    int kg = lane >> 4;

    f16x8 bf[NCT][2];
#pragma unroll
    for (int ct = 0; ct < NCT; ct++)
#pragma unroll
        for (int kt = 0; kt < 2; kt++)
            bf[ct][kt] = *reinterpret_cast<const f16x8*>(
                &wlds[(ct * 16 + r16) * WST + kt * 32 + kg * 8]);

    float4 bias4[NCT / 2];
#pragma unroll
    for (int ct = NCT / 2; ct < NCT; ct++)
        bias4[ct - NCT / 2] =
            *reinterpret_cast<const float4*>(bias + ct * 16 + kg * 4 - DOUT);

    int rbase = blockIdx.x * 256 + wv * 64;

#pragma unroll
    for (int rt = 0; rt < 4; rt++) {
        int row0 = rbase + rt * 16;
        int arow = row0 + r16;
        bool valid = arow < N;
        int ar = valid ? arow : (N - 1);

        f16x8 af[2];
        if (AFP32) {
            const float* Af = reinterpret_cast<const float*>(A) + (size_t)ar * 64;
#pragma unroll
            for (int kt = 0; kt < 2; kt++) {
                float4 u = *reinterpret_cast<const float4*>(Af + kt * 32 + kg * 8);
                float4 v = *reinterpret_cast<const float4*>(Af + kt * 32 + kg * 8 + 4);
                af[kt] = cvt2h(u, v);
            }
        } else {
            const f16* Ah = reinterpret_cast<const f16*>(A) + (size_t)ar * 64;
            af[0] = *reinterpret_cast<const f16x8*>(Ah + kg * 8);
            af[1] = *reinterpret_cast<const f16x8*>(Ah + 32 + kg * 8);
        }

        f32x4 acc[NCT];
#pragma unroll
        for (int ct = 0; ct < NCT; ct++) acc[ct] = (f32x4){0.f, 0.f, 0.f, 0.f};
#pragma unroll
        for (int kt = 0; kt < 2; kt++)
#pragma unroll
            for (int ct = 0; ct < NCT; ct++)
                acc[ct] = __builtin_amdgcn_mfma_f32_16x16x32_f16(
                    bf[ct][kt], af[kt], acc[ct], 0, 0, 0);

        if (valid) {
#pragma unroll
            for (int ct = 0; ct < NCT; ct++) {
                int c0 = ct * 16 + kg * 4;
                if (c0 < DOUT) {
                    f16x4 o;
                    o[0] = (_Float16)acc[ct][0]; o[1] = (_Float16)acc[ct][1];
                    o[2] = (_Float16)acc[ct][2]; o[3] = (_Float16)acc[ct][3];
                    *reinterpret_cast<f16x4*>(
                        reinterpret_cast<f16*>(Yp) + (size_t)arow * DOUT + c0) = o;
                } else {
                    float4 bv = bias4[ct - NCT / 2];
                    if (ZF16) {
                        f16x4 z;
                        z[0] = (_Float16)(acc[ct][0] + bv.x);
                        z[1] = (_Float16)(acc[ct][1] + bv.y);
                        z[2] = (_Float16)(acc[ct][2] + bv.z);
                        z[3] = (_Float16)(acc[ct][3] + bv.w);
                        *reinterpret_cast<f16x4*>(
                            reinterpret_cast<f16*>(Zp) + (size_t)arow * DOUT + (c0 - DOUT)) = z;
                    } else {
                        float4 z;
                        z.x = acc[ct][0] + bv.x; z.y = acc[ct][1] + bv.y;
                        z.z = acc[ct][2] + bv.z; z.w = acc[ct][3] + bv.w;
                        *reinterpret_cast<float4*>(
                            reinterpret_cast<float*>(Zp) + (size_t)arow * DOUT + (c0 - DOUT)) = z;
                    }
                }
            }
        }
    }
}

// ---------------- fused: h = relu(Z + mean gather(Y_in)) in LDS; then
//                  Y_out(fp16) = h @ Wl^T ; Z_out = h @ Wr^T + b ----------------
// Block = 128 nodes/rows, 4 waves. Phase A: 8-lane group per node, 4 passes.
// H-tile in LDS, stride 80 halves. Phase B: 2 row-tiles/wave, A-frags from LDS.
// Z strictly row-in-place (A reads row i before B writes row i, same block);
// Y double-buffered (gathers are cross-block).

template <int DOUT, bool ZF16OUT>
__global__ __launch_bounds__(256) void fused_agg_gemm_k(const int* __restrict__ rp,
                                                        const int* __restrict__ adj,
                                                        const __half* __restrict__ Yin,
                                                        const __half* __restrict__ Zin,
                                                        const float* __restrict__ Wl,
                                                        const float* __restrict__ Wr,
                                                        const float* __restrict__ bias,
                                                        __half* __restrict__ Yp,
                                                        void* __restrict__ Zp, int N) {
    constexpr int DOUT2 = 2 * DOUT;
    constexpr int NCT = DOUT2 / 16;
    constexpr int WST = 72;
    constexpr int HST = 80;
    __shared__ f16 wlds[DOUT2 * WST];
    __shared__ f16 hlds[128 * HST];
    int t = threadIdx.x;

    // stage next-layer weights fp32 -> fp16 (sync'd by the phase-A barrier)
    for (int i = t; i < DOUT2 * 16; i += 256) {
        int col = i >> 4, j4 = i & 15;
        const float* wsrc = (col < DOUT) ? (Wl + (size_t)col * 64)
                                         : (Wr + (size_t)(col - DOUT) * 64);
        float4 w = *reinterpret_cast<const float4*>(wsrc + j4 * 4);
        f16x4 o;
        o[0] = (_Float16)w.x; o[1] = (_Float16)w.y;
        o[2] = (_Float16)w.z; o[3] = (_Float16)w.w;
        *reinterpret_cast<f16x4*>(&wlds[col * WST + j4 * 4]) = o;
    }

    int lane = t & 63, wv = t >> 6;

    // ---- phase A: aggregate 128 nodes into hlds ----
    {
        int g = lane >> 3;      // group 0..7 (8 lanes each)
        int d8 = lane & 7;
        const float4* Y4 = reinterpret_cast<const float4*>(Yin);
#pragma unroll
        for (int pass = 0; pass < 4; ++pass) {
            int nl = wv * 32 + pass * 8 + g;
            int node = blockIdx.x * 128 + nl;
            if (node < N) {
                int s0 = rp[node], s1 = rp[node + 1];
                float acc[8];
#pragma unroll
                for (int k = 0; k < 8; k++) acc[k] = 0.f;
                int e = s0;
                for (; e + 4 <= s1; e += 4) {
                    int a0 = adj[e], a1 = adj[e + 1], a2 = adj[e + 2], a3 = adj[e + 3];
                    float4 r0 = Y4[(unsigned)a0 * 8 + d8];
                    float4 r1 = Y4[(unsigned)a1 * 8 + d8];
                    float4 r2 = Y4[(unsigned)a2 * 8 + d8];
                    float4 r3 = Y4[(unsigned)a3 * 8 + d8];
                    const __half2* h0 = reinterpret_cast<const __half2*>(&r0);
                    const __half2* h1 = reinterpret_cast<const __half2*>(&r1);
                    const __half2* h2 = reinterpret_cast<const __half2*>(&r2);
                    const __half2* h3 = reinterpret_cast<const __half2*>(&r3);
#pragma unroll
                    for (int k = 0; k < 4; k++) {
                        float2 f0 = __half22float2(h0[k]);
                        float2 f1 = __half22float2(h1[k]);
                        float2 f2 = __half22float2(h2[k]);
                        float2 f3 = __half22float2(h3[k]);
                        acc[2 * k]     += (f0.x + f1.x) + (f2.x + f3.x);
                        acc[2 * k + 1] += (f0.y + f1.y) + (f2.y + f3.y);
                    }
                }
                for (; e < s1; e++) {
                    float4 r0 = Y4[(unsigned)adj[e] * 8 + d8];
                    const __half2* h0 = reinterpret_cast<const __half2*>(&r0);
#pragma unroll
                    for (int k = 0; k < 4; k++) {
                        float2 f0 = __half22float2(h0[k]);
                        acc[2 * k] += f0.x;
                        acc[2 * k + 1] += f0.y;
                    }
                }
                int deg = s1 - s0;
                float inv = (deg > 0) ? 1.f / (float)deg : 0.f;
                f16x8 zf = *reinterpret_cast<const f16x8*>(
                    reinterpret_cast<const f16*>(Zin) + (size_t)node * 64 + d8 * 8);
                f16x8 o;
#pragma unroll
                for (int k = 0; k < 8; k++) {
                    float tv = (float)zf[k] + acc[k] * inv;
                    tv = fmaxf(tv, 0.f);   // relu (both fused layers)
                    o[k] = (_Float16)tv;
                }
                *reinterpret_cast<f16x8*>(&hlds[nl * HST + d8 * 8]) = o;
            }
        }
    }
    __syncthreads();

    // ---- phase B: GEMM on the LDS H-tile ----
    int r16 = lane & 15;
    int kg = lane >> 4;

    f16x8 bf[NCT][2];
#pragma unroll
    for (int ct = 0; ct < NCT; ct++)
#pragma unroll
        for (int kt = 0; kt < 2; kt++)
            bf[ct][kt] = *reinterpret_cast<const f16x8*>(
                &wlds[(ct * 16 + r16) * WST + kt * 32 + kg * 8]);

    float4 bias4[NCT / 2];
#pragma unroll
    for (int ct = NCT / 2; ct < NCT; ct++)
        bias4[ct - NCT / 2] =
            *reinterpret_cast<const float4*>(bias + ct * 16 + kg * 4 - DOUT);

#pragma unroll
    for (int rt = 0; rt < 2; rt++) {
        int rl = wv * 32 + rt * 16 + r16;
        int arow = blockIdx.x * 128 + rl;
        bool valid = arow < N;

        f16x8 af[2];
        af[0] = *reinterpret_cast<const f16x8*>(&hlds[rl * HST + kg * 8]);
        af[1] = *reinterpret_cast<const f16x8*>(&hlds[rl * HST + 32 + kg * 8]);

        f32x4 acc[NCT];
#pragma unroll
        for (int ct = 0; ct < NCT; ct++) acc[ct] = (f32x4){0.f, 0.f, 0.f, 0.f};
#pragma unroll
        for (int kt = 0; kt < 2; kt++)
#pragma unroll
            for (int ct = 0; ct < NCT; ct++)
                acc[ct] = __builtin_amdgcn_mfma_f32_16x16x32_f16(
                    bf[ct][kt], af[kt], acc[ct], 0, 0, 0);

        if (valid) {
#pragma unroll
            for (int ct = 0; ct < NCT; ct++) {
                int c0 = ct * 16 + kg * 4;
                if (c0 < DOUT) {
                    f16x4 o;
                    o[0] = (_Float16)acc[ct][0]; o[1] = (_Float16)acc[ct][1];
                    o[2] = (_Float16)acc[ct][2]; o[3] = (_Float16)acc[ct][3];
                    *reinterpret_cast<f16x4*>(
                        reinterpret_cast<f16*>(Yp) + (size_t)arow * DOUT + c0) = o;
                } else {
                    float4 bv = bias4[ct - NCT / 2];
                    if (ZF16OUT) {
                        f16x4 z;
                        z[0] = (_Float16)(acc[ct][0] + bv.x);
                        z[1] = (_Float16)(acc[ct][1] + bv.y);
                        z[2] = (_Float16)(acc[ct][2] + bv.z);
                        z[3] = (_Float16)(acc[ct][3] + bv.w);
                        *reinterpret_cast<f16x4*>(
                            reinterpret_cast<f16*>(Zp) + (size_t)arow * DOUT + (c0 - DOUT)) = z;
                    } else {
                        float4 z;
                        z.x = acc[ct][0] + bv.x; z.y = acc[ct][1] + bv.y;
                        z.z = acc[ct][2] + bv.z; z.w = acc[ct][3] + bv.w;
                        *reinterpret_cast<float4*>(
                            reinterpret_cast<float*>(Zp) + (size_t)arow * DOUT + (c0 - DOUT)) = z;
                    }
                }
            }
        }
    }
}

// ---------------- final aggregate (layer 2): out[i] += mean gather, fp32 in-place ----

template <int DOUT, bool RELU>
__global__ __launch_bounds__(256) void aggregate_k(const int* __restrict__ rp,
                                                   const int* __restrict__ adj,
                                                   const __half* __restrict__ Yh,
                                                   float* __restrict__ Hf, int N) {
    constexpr int FPR = DOUT / 8;        // 4 for d32
    constexpr int NPW = 64 / FPR;        // 16
    int wave = threadIdx.x >> 6;
    int lane = threadIdx.x & 63;
    int g = lane / FPR;
    int d8 = lane % FPR;
    int node = (blockIdx.x * 4 + wave) * NPW + g;
    if (node >= N) return;
    int s0 = rp[node], s1 = rp[node + 1];
    const float4* Y4 = reinterpret_cast<const float4*>(Yh);
    float acc[8];
#pragma unroll
    for (int k = 0; k < 8; k++) acc[k] = 0.f;

    int e = s0;
    for (; e + 4 <= s1; e += 4) {
        int a0 = adj[e], a1 = adj[e + 1], a2 = adj[e + 2], a3 = adj[e + 3];
        float4 r0 = Y4[(unsigned)a0 * FPR + d8];
        float4 r1 = Y4[(unsigned)a1 * FPR + d8];
        float4 r2 = Y4[(unsigned)a2 * FPR + d8];
        float4 r3 = Y4[(unsigned)a3 * FPR + d8];
        const __half2* h0 = reinterpret_cast<const __half2*>(&r0);
        const __half2* h1 = reinterpret_cast<const __half2*>(&r1);
        const __half2* h2 = reinterpret_cast<const __half2*>(&r2);
        const __half2* h3 = reinterpret_cast<const __half2*>(&r3);
#pragma unroll
        for (int k = 0; k < 4; k++) {
            float2 f0 = __half22float2(h0[k]);
            float2 f1 = __half22float2(h1[k]);
            float2 f2 = __half22float2(h2[k]);
            float2 f3 = __half22float2(h3[k]);
            acc[2 * k]     += (f0.x + f1.x) + (f2.x + f3.x);
            acc[2 * k + 1] += (f0.y + f1.y) + (f2.y + f3.y);
        }
    }
    for (; e < s1; e++) {
        float4 r0 = Y4[(unsigned)adj[e] * FPR + d8];
        const __half2* h0 = reinterpret_cast<const __half2*>(&r0);
#pragma unroll
        for (int k = 0; k < 4; k++) {
            float2 f0 = __half22float2(h0[k]);
            acc[2 * k] += f0.x;
            acc[2 * k + 1] += f0.y;
        }
    }
    int deg = s1 - s0;
    float inv = (deg > 0) ? 1.f / (float)deg : 0.f;
    float4* H4 = reinterpret_cast<float4*>(Hf);
    size_t hb = (size_t)node * (DOUT / 4) + d8 * 2;
    float4 v0 = H4[hb], v1 = H4[hb + 1];
    v0.x += acc[0] * inv; v0.y += acc[1] * inv;
    v0.z += acc[2] * inv; v0.w += acc[3] * inv;
    v1.x += acc[4] * inv; v1.y += acc[5] * inv;
    v1.z += acc[6] * inv; v1.w += acc[7] * inv;
    if (RELU) {
        v0.x = fmaxf(v0.x, 0.f); v0.y = fmaxf(v0.y, 0.f);
        v0.z = fmaxf(v0.z, 0.f); v0.w = fmaxf(v0.w, 0.f);
        v1.x = fmaxf(v1.x, 0.f); v1.y = fmaxf(v1.y, 0.f);
        v1.z = fmaxf(v1.z, 0.f); v1.w = fmaxf(v1.w, 0.f);
    }
    H4[hb] = v0;
    H4[hb + 1] = v1;
}

// ---------------- launch ----------------

extern "C" void kernel_launch(void* const* d_in, const int* in_sizes, int n_in,
                              void* d_out, int out_size, void* d_ws, size_t ws_size,
                              hipStream_t stream) {
    const float* x = (const float*)d_in[0];
    const int* ei = (const int*)d_in[1];  // int32
    const float* Wl0 = (const float*)d_in[3];
    const float* Wr0 = (const float*)d_in[4];
    const float* b0 = (const float*)d_in[5];
    const float* Wl1 = (const float*)d_in[6];
    const float* Wr1 = (const float*)d_in[7];
    const float* b1 = (const float*)d_in[8];
    const float* Wl2 = (const float*)d_in[9];
    const float* Wr2 = (const float*)d_in[10];
    const float* b2 = (const float*)d_in[11];

    int N = in_sizes[0] / 64;
    int E = in_sizes[1] / 2;
    const int* src = ei;
    const int* dstp = ei + E;

    char* ws = (char*)d_ws;
    size_t off = 0;
    auto take = [&](size_t bytes) -> void* {
        void* p = ws + off;
        off = (off + bytes + 255) & ~(size_t)255;
        return p;
    };
    int* rowptr = (int*)take((size_t)(N + 1) * 4);
    int* ghist = (int*)take((size_t)NBLK * MAXB * 4);
    int* colsum = (int*)take(MAXB * 4);
    int* bbase = (int*)take(MAXB * 4);
    int* adj = (int*)take((size_t)E * 4);
    __half* Ya = (__half*)take((size_t)N * 64 * 2);
    __half* Yb = (__half*)take((size_t)N * 64 * 2);
    __half* Zbuf = (__half*)take((size_t)N * 64 * 2);
    (void)ws_size;
    (void)n_in;
    (void)out_size;

    // pairs aliases Ya: CSR build fully precedes gemm0's writes to Ya,
    // and E*4 (6.4MB) <= N*64*2 (12.8MB).
    unsigned* pairs = (unsigned*)Ya;

    int nb = (N + 255) / 256;

    // CSR build (no global atomics)
    hist_k<<<NBLK, 256, 0, stream>>>(dstp, E, nb, ghist);
    col_scan_k<<<nb, 512, 0, stream>>>(ghist, colsum);
    bucket_scan_k<<<1, 512, 0, stream>>>(colsum, bbase, nb);
    partition_k<<<NBLK, 256, 0, stream>>>(src, dstp, ghist, bbase, pairs, E, nb);
    bucket_fill2_k<<<nb, 256, 0, stream>>>(pairs, bbase, colsum, rowptr, adj, N, E);

    float* out = (float*)d_out;
    int gb = (N + 255) / 256;    // gemm0: 256 rows/block
    int fb = (N + 127) / 128;    // fused: 128 rows/block
    int ab32 = (N + 63) / 64;    // final agg: 4 waves x 16 nodes

    // layer 0 transform: x (fp32) -> Ya, Zbuf(f16)
    gemm_mfma_k<64, true, true><<<gb, 256, 0, stream>>>(x, Wl0, Wr0, b0, Ya, Zbuf, N);
    // fused: agg0 (gather Ya, Z row-in-place) + gemm1 -> Yb, Zbuf
    fused_agg_gemm_k<64, true><<<fb, 256, 0, stream>>>(rowptr, adj, Ya, Zbuf,
                                                       Wl1, Wr1, b1, Yb, Zbuf, N);
    // fused: agg1 (gather Yb) + gemm2 -> Ya, out(fp32 self term)
    fused_agg_gemm_k<32, false><<<fb, 256, 0, stream>>>(rowptr, adj, Yb, Zbuf,
                                                        Wl2, Wr2, b2, Ya, out, N);
    // final aggregate: out += mean gather(Ya), no relu
    aggregate_k<32, false><<<ab32, 256, 0, stream>>>(rowptr, adj, Ya, out, N);
}

// Round 15
// 167.754 us; speedup vs baseline: 1.1555x; 1.1555x over previous
//
#include <hip/hip_runtime.h>
#include <hip/hip_fp16.h>

// GraphSAGE 3-layer encoder, MI355X.
// Transform-then-aggregate (mean agg is linear), CSR via atomic-free radix
// partition (R4). fp16 Y gather operand (R5), group-per-node aggregate (R6),
// unroll x4 (R7), fp16 activation chain (R8), swapped-operand MFMA GEMM with
// LDS-staged weights (R9), slice-ordered adjacency + fp16 Z (R10).
// R14: REVERT of the R13 fusion (fused kernel dropped aggregate occupancy
// 70% -> 17.6% by carrying 38.9KB LDS; latency-bound gather needs max TLP).
// This is the R10 structure: unfused LDS-free aggregates.

#define MAXB 512    // max node buckets (bucket = 256 nodes); N <= 131072
#define NBLK 512    // partition blocks (2 per CU)
#define NSLICE 8    // src slices (16384 nodes = 2MB fp16-d64 each)

typedef _Float16 f16;
typedef __attribute__((ext_vector_type(4))) _Float16 f16x4;
typedef __attribute__((ext_vector_type(8))) _Float16 f16x8;
typedef __attribute__((ext_vector_type(4))) float f32x4;

// ---- pass 1: per-block histogram over dst buckets ----
__global__ __launch_bounds__(256) void hist_k(const int* __restrict__ dst, int E,
                                              int nb, int* __restrict__ ghist) {
    __shared__ int h[MAXB];
    for (int i = threadIdx.x; i < nb; i += 256) h[i] = 0;
    __syncthreads();
    int chunk = (E + NBLK - 1) / NBLK;
    int e0 = blockIdx.x * chunk, e1 = min(e0 + chunk, E);
    for (int e = e0 + threadIdx.x; e < e1; e += 256) atomicAdd(&h[dst[e] >> 8], 1);
    __syncthreads();
    for (int i = threadIdx.x; i < nb; i += 256) ghist[blockIdx.x * MAXB + i] = h[i];
}

// ---- pass 2a: per-bucket exclusive scan over NBLK block counts (in place) ----
__global__ __launch_bounds__(512) void col_scan_k(int* __restrict__ ghist,
                                                  int* __restrict__ colsum) {
    int bucket = blockIdx.x;
    int t = threadIdx.x;
    __shared__ int s[NBLK];
    int v = ghist[t * MAXB + bucket];
    s[t] = v;
    __syncthreads();
    for (int off = 1; off < NBLK; off <<= 1) {
        int x = (t >= off) ? s[t - off] : 0;
        __syncthreads();
        s[t] += x;
        __syncthreads();
    }
    ghist[t * MAXB + bucket] = s[t] - v;  // exclusive prefix for this block
    if (t == NBLK - 1) colsum[bucket] = s[NBLK - 1];
}

// ---- pass 2b: exclusive scan of bucket totals ----
__global__ __launch_bounds__(512) void bucket_scan_k(const int* __restrict__ colsum,
                                                     int* __restrict__ bbase, int nb) {
    __shared__ int s[512];
    int t = threadIdx.x;
    int v = (t < nb) ? colsum[t] : 0;
    s[t] = v;
    __syncthreads();
    for (int off = 1; off < 512; off <<= 1) {
        int x = (t >= off) ? s[t - off] : 0;
        __syncthreads();
        s[t] += x;
        __syncthreads();
    }
    if (t < nb) bbase[t] = s[t] - v;
}

// ---- pass 3: scatter edges into private contiguous sub-ranges ----
__global__ __launch_bounds__(256) void partition_k(const int* __restrict__ src,
                                                   const int* __restrict__ dst,
                                                   const int* __restrict__ ghist,
                                                   const int* __restrict__ bbase,
                                                   unsigned* __restrict__ pairs,
                                                   int E, int nb) {
    __shared__ int cur[MAXB];
    for (int i = threadIdx.x; i < nb; i += 256)
        cur[i] = bbase[i] + ghist[blockIdx.x * MAXB + i];
    __syncthreads();
    int chunk = (E + NBLK - 1) / NBLK;
    int e0 = blockIdx.x * chunk, e1 = min(e0 + chunk, E);
    for (int e = e0 + threadIdx.x; e < e1; e += 256) {
        int d = dst[e];
        int b = d >> 8;
        int pos = atomicAdd(&cur[b], 1);               // LDS atomic only
        pairs[pos] = ((unsigned)(d & 255) << 24) | (unsigned)src[e];
    }
}

// ---- pass 4: per-(node,slice) count + scan -> rowptr + slice-ordered adj ----
__global__ __launch_bounds__(256) void bucket_fill2_k(const unsigned* __restrict__ pairs,
                                                      const int* __restrict__ bbase,
                                                      const int* __restrict__ colsum,
                                                      int* __restrict__ rowptr,
                                                      int* __restrict__ adj,
                                                      int N, int E) {
    int b = blockIdx.x, t = threadIdx.x;
    int node0 = b << 8;
    int nloc = min(256, N - node0);
    int e0 = bbase[b];
    int e1 = e0 + colsum[b];
    __shared__ int cnt[256 * NSLICE];   // 8 KB
    __shared__ int base[256 * NSLICE];  // 8 KB
    __shared__ int bs[256];
#pragma unroll
    for (int k = 0; k < NSLICE; k++) cnt[t * NSLICE + k] = 0;
    __syncthreads();
    for (int e = e0 + t; e < e1; e += 256) {
        unsigned p = pairs[e];
        int local = p >> 24;
        int s = (int)((p & 0xFFFFFFu) >> 14);
        atomicAdd(&cnt[local * NSLICE + s], 1);
    }
    __syncthreads();
    int lv[NSLICE];
    int lsum = 0;
#pragma unroll
    for (int k = 0; k < NSLICE; k++) { lv[k] = cnt[t * NSLICE + k]; lsum += lv[k]; }
    bs[t] = lsum;
    __syncthreads();
    for (int off = 1; off < 256; off <<= 1) {
        int x = (t >= off) ? bs[t - off] : 0;
        __syncthreads();
        bs[t] += x;
        __syncthreads();
    }
    int run = e0 + bs[t] - lsum;  // exclusive prefix at this node's first key
    if (t < nloc) rowptr[node0 + t] = run;
    if (b == 0 && t == 0) rowptr[N] = E;
#pragma unroll
    for (int k = 0; k < NSLICE; k++) { base[t * NSLICE + k] = run; run += lv[k]; }
#pragma unroll
    for (int k = 0; k < NSLICE; k++) cnt[t * NSLICE + k] = 0;
    __syncthreads();
    for (int e = e0 + t; e < e1; e += 256) {
        unsigned p = pairs[e];
        int local = p >> 24;
        int srcv = (int)(p & 0xFFFFFFu);
        int key = local * NSLICE + (srcv >> 14);
        int pos = base[key] + atomicAdd(&cnt[key], 1);  // LDS atomic only
        adj[pos] = srcv;
    }
}

// ---------------- MFMA dual GEMM: Y(fp16) = A @ Wl^T ; Z = A @ Wr^T + b --------------
// K = 64. Block = 256 rows (4 waves x 4 row-tiles of 16). Weights staged fp16
// in LDS once/block. SWAPPED mfma(W, H): D lane l reg r -> row (l&15),
// col kg*4+r (consecutive) -> vector stores. Z fp16 (layers 0/1) or fp32.

__device__ inline f16x8 cvt2h(float4 a, float4 b) {
    f16x8 o;
    o[0] = (_Float16)a.x; o[1] = (_Float16)a.y; o[2] = (_Float16)a.z; o[3] = (_Float16)a.w;
    o[4] = (_Float16)b.x; o[5] = (_Float16)b.y; o[6] = (_Float16)b.z; o[7] = (_Float16)b.w;
    return o;
}

template <int DOUT, bool AFP32, bool ZF16>
__global__ __launch_bounds__(256) void gemm_mfma_k(const void* __restrict__ A,
                                                   const float* __restrict__ Wl,
                                                   const float* __restrict__ Wr,
                                                   const float* __restrict__ bias,
                                                   __half* __restrict__ Yp,
                                                   void* __restrict__ Zp, int N) {
    constexpr int DOUT2 = 2 * DOUT;      // 128 or 64
    constexpr int NCT = DOUT2 / 16;      // 16-col tiles: 8 or 4
    constexpr int WST = 72;              // LDS row stride in halves (144 B)
    __shared__ f16 wlds[DOUT2 * WST];
    int t = threadIdx.x;

    // stage [Wl; Wr] fp32 -> fp16 into LDS as [col][k] (coalesced global reads)
    for (int i = t; i < DOUT2 * 16; i += 256) {
        int col = i >> 4, j4 = i & 15;
        const float* wsrc = (col < DOUT) ? (Wl + (size_t)col * 64)
                                         : (Wr + (size_t)(col - DOUT) * 64);
        float4 w = *reinterpret_cast<const float4*>(wsrc + j4 * 4);
        f16x4 o;
        o[0] = (_Float16)w.x; o[1] = (_Float16)w.y;
        o[2] = (_Float16)w.z; o[3] = (_Float16)w.w;
        *reinterpret_cast<f16x4*>(&wlds[col * WST + j4 * 4]) = o;
    }
    __syncthreads();

    int lane = t & 63, wv = t >> 6;
    int r16 = lane & 15;
    int kg = lane >> 4;                  // 0..3

    // W-frags from LDS, read once, reused across 4 row-tiles
    f16x8 bf[NCT][2];
#pragma unroll
    for (int ct = 0; ct < NCT; ct++)
#pragma unroll
        for (int kt = 0; kt < 2; kt++)
            bf[ct][kt] = *reinterpret_cast<const f16x8*>(
                &wlds[(ct * 16 + r16) * WST + kt * 32 + kg * 8]);

    // bias fragments (Z side): 4 consecutive cols per lane
    float4 bias4[NCT / 2];
#pragma unroll
    for (int ct = NCT / 2; ct < NCT; ct++)
        bias4[ct - NCT / 2] =
            *reinterpret_cast<const float4*>(bias + ct * 16 + kg * 4 - DOUT);

    int rbase = blockIdx.x * 256 + wv * 64;

#pragma unroll
    for (int rt = 0; rt < 4; rt++) {
        int row0 = rbase + rt * 16;
        int arow = row0 + r16;
        bool valid = arow < N;
        int ar = valid ? arow : (N - 1);

        f16x8 af[2];
        if (AFP32) {
            const float* Af = reinterpret_cast<const float*>(A) + (size_t)ar * 64;
#pragma unroll
            for (int kt = 0; kt < 2; kt++) {
                float4 u = *reinterpret_cast<const float4*>(Af + kt * 32 + kg * 8);
                float4 v = *reinterpret_cast<const float4*>(Af + kt * 32 + kg * 8 + 4);
                af[kt] = cvt2h(u, v);
            }
        } else {
            const f16* Ah = reinterpret_cast<const f16*>(A) + (size_t)ar * 64;
            af[0] = *reinterpret_cast<const f16x8*>(Ah + kg * 8);
            af[1] = *reinterpret_cast<const f16x8*>(Ah + 32 + kg * 8);
        }

        f32x4 acc[NCT];
#pragma unroll
        for (int ct = 0; ct < NCT; ct++) acc[ct] = (f32x4){0.f, 0.f, 0.f, 0.f};
#pragma unroll
        for (int kt = 0; kt < 2; kt++)
#pragma unroll
            for (int ct = 0; ct < NCT; ct++)
                acc[ct] = __builtin_amdgcn_mfma_f32_16x16x32_f16(
                    bf[ct][kt], af[kt], acc[ct], 0, 0, 0);  // SWAPPED operands

        if (valid) {
#pragma unroll
            for (int ct = 0; ct < NCT; ct++) {
                int c0 = ct * 16 + kg * 4;
                if (c0 < DOUT) {
                    f16x4 o;
                    o[0] = (_Float16)acc[ct][0]; o[1] = (_Float16)acc[ct][1];
                    o[2] = (_Float16)acc[ct][2]; o[3] = (_Float16)acc[ct][3];
                    *reinterpret_cast<f16x4*>(
                        reinterpret_cast<f16*>(Yp) + (size_t)arow * DOUT + c0) = o;
                } else {
                    float4 bv = bias4[ct - NCT / 2];
                    if (ZF16) {
                        f16x4 z;
                        z[0] = (_Float16)(acc[ct][0] + bv.x);
                        z[1] = (_Float16)(acc[ct][1] + bv.y);
                        z[2] = (_Float16)(acc[ct][2] + bv.z);
                        z[3] = (_Float16)(acc[ct][3] + bv.w);
                        *reinterpret_cast<f16x4*>(
                            reinterpret_cast<f16*>(Zp) + (size_t)arow * DOUT + (c0 - DOUT)) = z;
                    } else {
                        float4 z;
                        z.x = acc[ct][0] + bv.x; z.y = acc[ct][1] + bv.y;
                        z.z = acc[ct][2] + bv.z; z.w = acc[ct][3] + bv.w;
                        *reinterpret_cast<float4*>(
                            reinterpret_cast<float*>(Zp) + (size_t)arow * DOUT + (c0 - DOUT)) = z;
                    }
                }
            }
        }
    }
}

// ---------------- aggregate: out[i] = act(Z[i] + mean_{e} Y[adj[e]]) ----------------
// Y fp16. FPR lanes per node; lane d8 owns 8 dims end-to-end. Gather unroll x4.
// OUTF16: read Z fp16, write H fp16. else: in-place fp32 (final layer).

template <int DOUT, bool RELU, bool OUTF16>
__global__ __launch_bounds__(256) void aggregate_k(const int* __restrict__ rp,
                                                   const int* __restrict__ adj,
                                                   const __half* __restrict__ Yh,
                                                   const __half* __restrict__ Zh,
                                                   __half* __restrict__ Ho,
                                                   float* __restrict__ Hf, int N) {
    constexpr int FPR = DOUT / 8;        // lanes per node: 8 (d64) or 4 (d32)
    constexpr int NPW = 64 / FPR;        // nodes per wave: 8 or 16
    int wave = threadIdx.x >> 6;
    int lane = threadIdx.x & 63;
    int g = lane / FPR;
    int d8 = lane % FPR;
    int node = (blockIdx.x * 4 + wave) * NPW + g;
    if (node >= N) return;
    int s0 = rp[node], s1 = rp[node + 1];
    const float4* Y4 = reinterpret_cast<const float4*>(Yh);
    float acc[8];
#pragma unroll
    for (int k = 0; k < 8; k++) acc[k] = 0.f;

    int e = s0;
    for (; e + 4 <= s1; e += 4) {
        int a0 = adj[e], a1 = adj[e + 1], a2 = adj[e + 2], a3 = adj[e + 3];
        float4 r0 = Y4[(unsigned)a0 * FPR + d8];
        float4 r1 = Y4[(unsigned)a1 * FPR + d8];
        float4 r2 = Y4[(unsigned)a2 * FPR + d8];
        float4 r3 = Y4[(unsigned)a3 * FPR + d8];
        const __half2* h0 = reinterpret_cast<const __half2*>(&r0);
        const __half2* h1 = reinterpret_cast<const __half2*>(&r1);
        const __half2* h2 = reinterpret_cast<const __half2*>(&r2);
        const __half2* h3 = reinterpret_cast<const __half2*>(&r3);
#pragma unroll
        for (int k = 0; k < 4; k++) {
            float2 f0 = __half22float2(h0[k]);
            float2 f1 = __half22float2(h1[k]);
            float2 f2 = __half22float2(h2[k]);
            float2 f3 = __half22float2(h3[k]);
            acc[2 * k]     += (f0.x + f1.x) + (f2.x + f3.x);
            acc[2 * k + 1] += (f0.y + f1.y) + (f2.y + f3.y);
        }
    }
    for (; e < s1; e++) {
        float4 r0 = Y4[(unsigned)adj[e] * FPR + d8];
        const __half2* h0 = reinterpret_cast<const __half2*>(&r0);
#pragma unroll
        for (int k = 0; k < 4; k++) {
            float2 f0 = __half22float2(h0[k]);
            acc[2 * k] += f0.x;
            acc[2 * k + 1] += f0.y;
        }
    }
    int deg = s1 - s0;
    float inv = (deg > 0) ? 1.f / (float)deg : 0.f;

    if constexpr (OUTF16) {
        f16x8 zf = *reinterpret_cast<const f16x8*>(
            reinterpret_cast<const f16*>(Zh) + (size_t)node * DOUT + d8 * 8);
        f16x8 o;
#pragma unroll
        for (int k = 0; k < 8; k++) {
            float tv = (float)zf[k] + acc[k] * inv;
            if (RELU) tv = fmaxf(tv, 0.f);
            o[k] = (_Float16)tv;
        }
        *reinterpret_cast<f16x8*>(reinterpret_cast<f16*>(Ho) + (size_t)node * DOUT + d8 * 8) = o;
    } else {
        float4* H4 = reinterpret_cast<float4*>(Hf);
        size_t hb = (size_t)node * (DOUT / 4) + d8 * 2;
        float4 v0 = H4[hb], v1 = H4[hb + 1];
        v0.x += acc[0] * inv; v0.y += acc[1] * inv;
        v0.z += acc[2] * inv; v0.w += acc[3] * inv;
        v1.x += acc[4] * inv; v1.y += acc[5] * inv;
        v1.z += acc[6] * inv; v1.w += acc[7] * inv;
        if (RELU) {
            v0.x = fmaxf(v0.x, 0.f); v0.y = fmaxf(v0.y, 0.f);
            v0.z = fmaxf(v0.z, 0.f); v0.w = fmaxf(v0.w, 0.f);
            v1.x = fmaxf(v1.x, 0.f); v1.y = fmaxf(v1.y, 0.f);
            v1.z = fmaxf(v1.z, 0.f); v1.w = fmaxf(v1.w, 0.f);
        }
        H4[hb] = v0;
        H4[hb + 1] = v1;
    }
}

// ---------------- launch ----------------

extern "C" void kernel_launch(void* const* d_in, const int* in_sizes, int n_in,
                              void* d_out, int out_size, void* d_ws, size_t ws_size,
                              hipStream_t stream) {
    const float* x = (const float*)d_in[0];
    const int* ei = (const int*)d_in[1];  // int32
    const float* Wl0 = (const float*)d_in[3];
    const float* Wr0 = (const float*)d_in[4];
    const float* b0 = (const float*)d_in[5];
    const float* Wl1 = (const float*)d_in[6];
    const float* Wr1 = (const float*)d_in[7];
    const float* b1 = (const float*)d_in[8];
    const float* Wl2 = (const float*)d_in[9];
    const float* Wr2 = (const float*)d_in[10];
    const float* b2 = (const float*)d_in[11];

    int N = in_sizes[0] / 64;
    int E = in_sizes[1] / 2;
    const int* src = ei;
    const int* dstp = ei + E;

    char* ws = (char*)d_ws;
    size_t off = 0;
    auto take = [&](size_t bytes) -> void* {
        void* p = ws + off;
        off = (off + bytes + 255) & ~(size_t)255;
        return p;
    };
    int* rowptr = (int*)take((size_t)(N + 1) * 4);
    int* ghist = (int*)take((size_t)NBLK * MAXB * 4);
    int* colsum = (int*)take(MAXB * 4);
    int* bbase = (int*)take(MAXB * 4);
    int* adj = (int*)take((size_t)E * 4);
    __half* Yh = (__half*)take((size_t)N * 64 * 2);
    __half* Zbuf = (__half*)take((size_t)N * 64 * 2);
    __half* HA = (__half*)take((size_t)N * 64 * 2);
    __half* HB = (__half*)take((size_t)N * 64 * 2);
    (void)ws_size;
    (void)n_in;
    (void)out_size;

    // pairs buffer aliases Yh: CSR build fully precedes gemm0's writes to Yh,
    // and E*4 (6.4MB) <= N*64*2 (12.8MB).
    unsigned* pairs = (unsigned*)Yh;

    int nb = (N + 255) / 256;

    // CSR build (no global atomics)
    hist_k<<<NBLK, 256, 0, stream>>>(dstp, E, nb, ghist);
    col_scan_k<<<nb, 512, 0, stream>>>(ghist, colsum);
    bucket_scan_k<<<1, 512, 0, stream>>>(colsum, bbase, nb);
    partition_k<<<NBLK, 256, 0, stream>>>(src, dstp, ghist, bbase, pairs, E, nb);
    bucket_fill2_k<<<nb, 256, 0, stream>>>(pairs, bbase, colsum, rowptr, adj, N, E);

    float* out = (float*)d_out;
    int gb = (N + 255) / 256;    // 256 rows per block
    int ab64 = (N + 31) / 32;    // 4 waves x 8 nodes
    int ab32 = (N + 63) / 64;    // 4 waves x 16 nodes

    // layer 0: x (fp32) -> Yh, Zbuf(f16); agg -> HA (fp16, relu)
    gemm_mfma_k<64, true, true><<<gb, 256, 0, stream>>>(x, Wl0, Wr0, b0, Yh, Zbuf, N);
    aggregate_k<64, true, true><<<ab64, 256, 0, stream>>>(rowptr, adj, Yh, Zbuf, HA, nullptr, N);
    // layer 1: HA -> Yh, Zbuf(f16); agg -> HB (fp16, relu)
    gemm_mfma_k<64, false, true><<<gb, 256, 0, stream>>>(HA, Wl1, Wr1, b1, Yh, Zbuf, N);
    aggregate_k<64, true, true><<<ab64, 256, 0, stream>>>(rowptr, adj, Yh, Zbuf, HB, nullptr, N);
    // layer 2: HB -> Yh, out(fp32); agg in-place fp32, no relu
    gemm_mfma_k<32, false, false><<<gb, 256, 0, stream>>>(HB, Wl2, Wr2, b2, Yh, out, N);
    aggregate_k<32, false, false><<<ab32, 256, 0, stream>>>(rowptr, adj, Yh, nullptr, nullptr, out, N);
}